// Round 5
// baseline (6746.366 us; speedup 1.0000x reference)
//
#include <hip/hip_runtime.h>

#define BATCH 512
#define TT 64
#define II 128

// ---------------- workspace layout (floats) ----------------
#define OFF_Wr_e0 0                         // [512][256] rows: [Wih0(x,pad)|Whh0(h0)]
#define OFF_Wr_e1 (OFF_Wr_e0 + 512*256)     // [512][256] rows: [Wih1(h0)|Whh1(h1)]
#define OFF_Wr_d1 (OFF_Wr_e1 + 512*256)     // [512][256] rows: [dWih1(h0)|dWhh1(h1)]
#define OFF_bs0e  (OFF_Wr_d1 + 512*256)
#define OFF_bs1e  (OFF_bs0e + 512)
#define OFF_bs0d  (OFF_bs1e + 512)
#define OFF_bs1d  (OFF_bs0d + 512)
#define OFF_xprojT (OFF_bs1d + 512)          // [B][64j][128e]
#define OFF_hexp   (OFF_xprojT + BATCH*8192) // [B][64t][128k]
#define OFF_hprojT (OFF_hexp + BATCH*8192)   // [B][128kk][64t]

struct Params {
  const float* input;
  const float *eWih0, *eWhh0, *ebih0, *ebhh0, *eWih1, *eWhh1, *ebih1, *ebhh1;
  const float *dWih0, *dWhh0, *dbih0, *dbhh0, *dWih1, *dWhh1, *dbih1, *dbhh1;
  const float *aW1, *ab1, *aW2, *ab2;
  const float *adW1, *adb1, *adW2, *adb2;
  const float *dinW, *dinb, *projW, *projb;
  float* ws;
  float* out;
};

#define L2E 1.4426950408889634f

__device__ __forceinline__ float exp2f_(float x){ return __builtin_amdgcn_exp2f(x); }
__device__ __forceinline__ float rcp_(float x){ return __builtin_amdgcn_rcpf(x); }
__device__ __forceinline__ float fast_tanh(float x){
  float t = exp2f_(x * 2.8853900817779268f);   // e^{2x}
  return 1.f - 2.f * rcp_(t + 1.f);
}
__device__ __forceinline__ float sigm(float x){
  return rcp_(1.f + exp2f_(-x * L2E));
}
__device__ __forceinline__ float wave_max(float v){
  #pragma unroll
  for (int o = 32; o > 0; o >>= 1) v = fmaxf(v, __shfl_xor(v, o, 64));
  return v;
}
__device__ __forceinline__ float wave_sum(float v){
  #pragma unroll
  for (int o = 32; o > 0; o >>= 1) v += __shfl_xor(v, o, 64);
  return v;
}

#define DOT(A,W,X) A += (W).x*(X).x + (W).y*(X).y + (W).z*(X).z + (W).w*(X).w;
#define CMB2(A) A += __shfl_xor(A,1,64); A += __shfl_xor(A,2,64);
#define CMB3(A) CMB2(A) A += __shfl_xor(A,4,64);
#define DECL16 float a00=0,a10=0,a20=0,a30=0,a01=0,a11=0,a21=0,a31=0, \
                     a02=0,a12=0,a22=0,a32=0,a03=0,a13=0,a23=0,a33=0;
#define GEMM16(WA,WB,WC,WD,XA,XB,XC,XD) \
  DOT(a00,WA,XA) DOT(a10,WB,XA) DOT(a20,WC,XA) DOT(a30,WD,XA) \
  DOT(a01,WA,XB) DOT(a11,WB,XB) DOT(a21,WC,XB) DOT(a31,WD,XB) \
  DOT(a02,WA,XC) DOT(a12,WB,XC) DOT(a22,WC,XC) DOT(a32,WD,XC) \
  DOT(a03,WA,XD) DOT(a13,WB,XD) DOT(a23,WC,XD) DOT(a33,WD,XD)
#define CMB2ALL16 CMB2(a00) CMB2(a10) CMB2(a20) CMB2(a30) CMB2(a01) CMB2(a11) \
  CMB2(a21) CMB2(a31) CMB2(a02) CMB2(a12) CMB2(a22) CMB2(a32) CMB2(a03) \
  CMB2(a13) CMB2(a23) CMB2(a33)

// ---------------- prep ----------------
__global__ __launch_bounds__(256) void k_prep(Params p){
  float* ws = p.ws;
  const int gid = blockIdx.x*256 + threadIdx.x;
  const int gsz = gridDim.x*256;
  for (int i = gid; i < 512*256; i += gsz){
    const int j = i >> 8, k = i & 255;
    ws[OFF_Wr_e0 + i] = (k < 128) ? ((k < 127) ? p.eWih0[j*127 + k] : 0.f)
                                  : p.eWhh0[j*128 + (k-128)];
    ws[OFF_Wr_e1 + i] = (k < 128) ? p.eWih1[j*128 + k] : p.eWhh1[j*128 + (k-128)];
    ws[OFF_Wr_d1 + i] = (k < 128) ? p.dWih1[j*128 + k] : p.dWhh1[j*128 + (k-128)];
  }
  for (int i = gid; i < 512; i += gsz){
    ws[OFF_bs0e+i] = p.ebih0[i]+p.ebhh0[i];
    ws[OFF_bs1e+i] = p.ebih1[i]+p.ebhh1[i];
    ws[OFF_bs0d+i] = p.dbih0[i]+p.dbhh0[i];
    ws[OFF_bs1d+i] = p.dbih1[i]+p.dbhh1[i];
  }
}

// ---------------- xprojT[b][j][e] ----------------
__global__ __launch_bounds__(256) void k_xproj(Params p){
  __shared__ float xin[64][128];
  __shared__ float w1x[64][64];
  __shared__ float b1s[64];
  const int b = blockIdx.x, tid = threadIdx.x;
  const float* inb = p.input + (size_t)b*(TT*II);
  for (int i = tid; i < 64*128; i += 256){
    const int k = i >> 7, e = i & 127;
    xin[k][e] = (e < 127) ? inb[k*II + 1 + e] : 0.f;
  }
  for (int i = tid; i < 64*64; i += 256){
    const int j = i >> 6, k = i & 63;
    w1x[j][k] = p.aW1[j*320 + 256 + k];
  }
  if (tid < 64) b1s[tid] = p.ab1[tid];
  __syncthreads();
  float* outb = p.ws + OFF_xprojT + (size_t)b*8192;
  for (int i = tid; i < 64*128; i += 256){
    const int j = i >> 7, e = i & 127;
    float acc = b1s[j];
    #pragma unroll 8
    for (int k = 0; k < 64; ++k) acc += xin[k][e] * w1x[j][k];
    outb[i] = acc;
  }
}

// ---------------- hprojT[b][kk][t] ----------------
__global__ __launch_bounds__(256) void k_hproj(Params p){
  __shared__ float hx[64][129];
  __shared__ float bs[128];
  const int b = blockIdx.x, tid = threadIdx.x;
  const float* hb = p.ws + OFF_hexp + (size_t)b*8192;
  for (int i = tid; i < 64*128; i += 256) hx[i>>7][i&127] = hb[i];
  if (tid < 128) bs[tid] = p.adb1[tid];
  __syncthreads();
  float* outb = p.ws + OFF_hprojT + (size_t)b*8192;
  for (int i = tid; i < 128*64; i += 256){
    const int kk = i >> 6, t2 = i & 63;
    const float* w = p.adW1 + kk*384 + 256;
    float acc = bs[kk];
    #pragma unroll 8
    for (int k = 0; k < 128; ++k) acc += hx[t2][k] * w[k];
    outb[i] = acc;
  }
}

// ---------------- encoder: 128 blocks x 4 batches, 512 threads --------------
// LDS floats: xp 32768 | Se 2048 | c0s 512 | gp 2048 | g01s 256 | w2 64 | pm 8 | psu 8
#define ENC_LDS_FLOATS (32768+2048+512+2048+256+64+8+8)
__global__ __launch_bounds__(512, 2) void k_enc(Params p){
  extern __shared__ float sm[];
  float* xp   = sm;
  float* Se   = xp + 32768;    // [bb][x|h0|h1|c1] 4x512
  float* c0s  = Se + 2048;
  float* gp   = c0s + 512;     // [bb][512]
  float* g01s = gp + 2048;     // [bb][64]
  float* w2   = g01s + 256;
  float* pm   = w2 + 64;
  float* psu  = pm + 8;
  const int tid = threadIdx.x;
  const int b0 = blockIdx.x*4;
  float* ws = p.ws;

  { const float4* xsrc = (const float4*)(ws + OFF_xprojT + (size_t)b0*8192);
    float4* xdst = (float4*)xp;
    for (int i = tid; i < 8192; i += 512) xdst[i] = xsrc[i]; }
  for (int i = tid; i < 2048; i += 512) Se[i] = 0.f;
  c0s[tid] = 0.f;
  if (tid < 64) w2[tid] = p.aW2[tid];
  const float b2 = p.ab2[0];

  // thread maps
  const int kq8 = tid & 7, jjE = tid >> 3;             // E1 (K=256, 8-split)
  const int k0q8 = kq8 << 5;
  const int e2 = tid & 127, bb2 = tid >> 7;            // E2
  const int ehalf = (tid >> 6) & 1;
  const int kq4 = tid & 3, gE = tid >> 2;              // E3/E4 (R=4, 4-split)
  const int j0 = gE << 2;
  const int k0q4 = kq4 << 6;
  const int bbU = tid >> 7, uU = tid & 127;            // updates

  const float4 bias0v = *(const float4*)(ws + OFF_bs0e + j0);
  const float4 bias1v = *(const float4*)(ws + OFF_bs1e + j0);
  const int offE1 = jjE*320 + k0q8;                    // into aW1 (cols 0..255 = h|c)
  const int offE3 = OFF_Wr_e0 + j0*256 + k0q4;
  const int offE4 = OFF_Wr_e1 + j0*256 + k0q4;
  __syncthreads();

  for (int t = 0; t < TT; ++t){
    // --- E1: g01[bb][jj] = sum_k [h1|c1]·aW1[jj][k], 8-way K-split
    {
      float a0=0.f,a1=0.f,a2=0.f,a3=0.f;
      #pragma unroll
      for (int kg = 0; kg < 8; ++kg){
        const int idx = (((kg + kq8) & 7) << 2);       // bank-rotated
        const float4 w  = *(const float4*)(p.aW1 + offE1 + idx);
        const float4 v0 = *(const float4*)(Se + 256 + k0q8 + idx);
        const float4 v1 = *(const float4*)(Se + 768 + k0q8 + idx);
        const float4 v2 = *(const float4*)(Se + 1280 + k0q8 + idx);
        const float4 v3 = *(const float4*)(Se + 1792 + k0q8 + idx);
        DOT(a0,w,v0) DOT(a1,w,v1) DOT(a2,w,v2) DOT(a3,w,v3)
      }
      CMB3(a0) CMB3(a1) CMB3(a2) CMB3(a3)
      if (kq8 == 0){
        g01s[jjE] = a0; g01s[64+jjE] = a1; g01s[128+jjE] = a2; g01s[192+jjE] = a3;
      }
    }
    __syncthreads();
    // --- E2a: logits (full j per thread) + per-wave softmax partials
    float accL;
    {
      const float* xpe = xp + bb2*8192 + e2;
      const float* gg = g01s + bb2*64;
      float a = b2;
      #pragma unroll 8
      for (int j = 0; j < 64; ++j)
        a += w2[j] * fast_tanh(xpe[j*128] + gg[j]);
      if (e2 == 127) a = -3.0e38f;
      accL = a;
      const float m = wave_max(a);
      const float pe = exp2f_((a - m)*L2E);
      const float s = wave_sum(pe);
      if ((tid & 63) == 0){ pm[bb2*2+ehalf] = m; psu[bb2*2+ehalf] = s; }
    }
    __syncthreads();
    // --- E2c: finish softmax, Se.x = a * x_t
    {
      const float m0 = pm[bb2*2], m1 = pm[bb2*2+1];
      const float gm = fmaxf(m0,m1);
      const float tot = psu[bb2*2]*exp2f_((m0-gm)*L2E) + psu[bb2*2+1]*exp2f_((m1-gm)*L2E);
      const float aa = exp2f_((accL-gm)*L2E)*rcp_(tot);
      float xv = 0.f;
      if (e2 < 127) xv = p.input[(size_t)(b0+bb2)*8192 + t*128 + 1 + e2] * aa;
      Se[bb2*512 + e2] = xv;
    }
    __syncthreads();
    // --- E3: layer0 gates, rows j0..j0+3, operand Se[0..255] (x|h0)
    {
      DECL16
      #pragma unroll 4
      for (int kg = 0; kg < 16; ++kg){
        const int idx = (((kg + kq4*2) & 15) << 2);
        const float4 wA = *(const float4*)(ws + offE3 + idx);
        const float4 wB = *(const float4*)(ws + offE3 + 256 + idx);
        const float4 wC = *(const float4*)(ws + offE3 + 512 + idx);
        const float4 wD = *(const float4*)(ws + offE3 + 768 + idx);
        const float4 xA = *(const float4*)(Se + k0q4 + idx);
        const float4 xB = *(const float4*)(Se + 512 + k0q4 + idx);
        const float4 xC = *(const float4*)(Se + 1024 + k0q4 + idx);
        const float4 xD = *(const float4*)(Se + 1536 + k0q4 + idx);
        GEMM16(wA,wB,wC,wD,xA,xB,xC,xD);
      }
      CMB2ALL16
      if (kq4 == 0){
        *(float4*)(gp + j0)        = make_float4(a00+bias0v.x, a10+bias0v.y, a20+bias0v.z, a30+bias0v.w);
        *(float4*)(gp + 512 + j0)  = make_float4(a01+bias0v.x, a11+bias0v.y, a21+bias0v.z, a31+bias0v.w);
        *(float4*)(gp + 1024 + j0) = make_float4(a02+bias0v.x, a12+bias0v.y, a22+bias0v.z, a32+bias0v.w);
        *(float4*)(gp + 1536 + j0) = make_float4(a03+bias0v.x, a13+bias0v.y, a23+bias0v.z, a33+bias0v.w);
      }
    }
    __syncthreads();
    // --- A0: update h0, c0
    {
      const float* g = gp + bbU*512;
      const float gi=g[uU], gf=g[128+uU], gg2=g[256+uU], go=g[384+uU];
      const float c = sigm(gf)*c0s[tid] + sigm(gi)*fast_tanh(gg2);
      c0s[tid] = c;
      Se[bbU*512 + 128 + uU] = sigm(go)*fast_tanh(c);
    }
    __syncthreads();
    // --- E4: layer1 gates, operand Se[128..383] (h0|h1)
    {
      DECL16
      #pragma unroll 4
      for (int kg = 0; kg < 16; ++kg){
        const int idx = (((kg + kq4*2) & 15) << 2);
        const float4 wA = *(const float4*)(ws + offE4 + idx);
        const float4 wB = *(const float4*)(ws + offE4 + 256 + idx);
        const float4 wC = *(const float4*)(ws + offE4 + 512 + idx);
        const float4 wD = *(const float4*)(ws + offE4 + 768 + idx);
        const float4 xA = *(const float4*)(Se + 128 + k0q4 + idx);
        const float4 xB = *(const float4*)(Se + 640 + k0q4 + idx);
        const float4 xC = *(const float4*)(Se + 1152 + k0q4 + idx);
        const float4 xD = *(const float4*)(Se + 1664 + k0q4 + idx);
        GEMM16(wA,wB,wC,wD,xA,xB,xC,xD);
      }
      CMB2ALL16
      if (kq4 == 0){
        *(float4*)(gp + j0)        = make_float4(a00+bias1v.x, a10+bias1v.y, a20+bias1v.z, a30+bias1v.w);
        *(float4*)(gp + 512 + j0)  = make_float4(a01+bias1v.x, a11+bias1v.y, a21+bias1v.z, a31+bias1v.w);
        *(float4*)(gp + 1024 + j0) = make_float4(a02+bias1v.x, a12+bias1v.y, a22+bias1v.z, a32+bias1v.w);
        *(float4*)(gp + 1536 + j0) = make_float4(a03+bias1v.x, a13+bias1v.y, a23+bias1v.z, a33+bias1v.w);
      }
    }
    __syncthreads();
    // --- A1: update h1,c1, write hexp
    {
      const float* g = gp + bbU*512;
      const float gi=g[uU], gf=g[128+uU], gg2=g[256+uU], go=g[384+uU];
      const float c = sigm(gf)*Se[bbU*512+384+uU] + sigm(gi)*fast_tanh(gg2);
      Se[bbU*512+384+uU] = c;
      const float h = sigm(go)*fast_tanh(c);
      Se[bbU*512+256+uU] = h;
      ws[OFF_hexp + (size_t)(b0+bbU)*8192 + t*128 + uU] = h;
    }
    __syncthreads();
  }
}

// ---------------- decoder: 128 blocks x 4 batches, 512 threads --------------
// LDS floats: hp 33280 | Sd 1536 | c0s 512 | gp 2048 | g01d 512 | lraw 256
//             pm 8 | psu 8 | dpart 8 | wd2 128 | parts 512  = 38808
#define DEC_LDS_FLOATS (33280+1536+512+2048+512+256+8+8+8+128+512)
__global__ __launch_bounds__(512, 2) void k_dec(Params p){
  extern __shared__ float sm[];
  float* hp    = sm;            // [bb][kk][65]
  float* Sd    = hp + 33280;    // [bb][h0|h1|c1] 4x384
  float* c0s   = Sd + 1536;
  float* gp    = c0s + 512;
  float* g01d  = gp + 2048;     // [bb][128]
  float* lraw  = g01d + 512;    // [bb][64], softmax in place
  float* pm    = lraw + 256;
  float* psu   = pm + 8;
  float* dpart = psu + 8;
  float* wd2   = dpart + 8;
  float* parts = wd2 + 128;     // [bb][128]
  const int tid = threadIdx.x;
  const int b0 = blockIdx.x*4;
  float* ws = p.ws;

  { const float* hsrc = ws + OFF_hprojT + (size_t)b0*8192;
    for (int i = tid; i < 32768; i += 512){
      const int bb = i>>13, kk = (i>>6)&127, tl = i&63;
      hp[bb*8320 + kk*65 + tl] = hsrc[i];
    } }
  for (int i = tid; i < 1536; i += 512) Sd[i] = 0.f;
  c0s[tid] = 0.f;
  if (tid < 128) wd2[tid] = p.adW2[tid];
  const float bd2 = p.adb2[0];

  // thread maps
  const int kq8 = tid & 7, gD1 = tid >> 3;            // D1 (R=2, 8-split)
  const int kk0 = gD1 << 1, k0d1 = kq8 << 5;
  const int kqA = tid & 1, tlA = (tid>>1) & 63, bbA = tid >> 7;  // D2a
  const int tlh = (tid>>6) & 1;
  const int hC = tid & 127, bbC = tid >> 7, hh = (tid>>6) & 1;   // D2c
  const int kq4 = tid & 3, gG = tid >> 2;             // D3/D4 (R=4)
  const int j0 = gG << 2;
  const int k0d3 = kq4 << 5, k0d4 = kq4 << 6;
  const int bbU = tid >> 7, uU = tid & 127;

  const float4 bias0d4 = *(const float4*)(ws + OFF_bs0d + j0);
  const float4 bias1d4 = *(const float4*)(ws + OFF_bs1d + j0);
  const float4 dW0v = *(const float4*)(p.dWih0 + j0);
  const int offD1 = kk0*384 + k0d1;                   // into adW1 (cols 0..255)
  const int offD3 = j0*128 + k0d3;                    // into dWhh0
  const int offD4 = OFF_Wr_d1 + j0*256 + k0d4;
  const int heBase = OFF_hexp + (b0+bbC)*8192 + hC;
  const float wdin_h = p.dinW[hC];
  const float dinw128 = p.dinW[128], dinbv = p.dinb[0];
  __syncthreads();

  for (int t = 0; t < TT; ++t){
    // --- D1: g01d[bb][kk0..kk0+1] over K=256 [h1|c1], 8-way split
    {
      float a00=0,a01=0,a02=0,a03=0,a10=0,a11=0,a12=0,a13=0;  // a{r}{b}
      #pragma unroll
      for (int kg = 0; kg < 8; ++kg){
        const int idx = (((kg + kq8) & 7) << 2);
        const float4 w0 = *(const float4*)(p.adW1 + offD1 + idx);
        const float4 w1 = *(const float4*)(p.adW1 + offD1 + 384 + idx);
        const float4 x0 = *(const float4*)(Sd + 128 + k0d1 + idx);
        const float4 x1 = *(const float4*)(Sd + 512 + k0d1 + idx);
        const float4 x2 = *(const float4*)(Sd + 896 + k0d1 + idx);
        const float4 x3 = *(const float4*)(Sd + 1280 + k0d1 + idx);
        DOT(a00,w0,x0) DOT(a01,w0,x1) DOT(a02,w0,x2) DOT(a03,w0,x3)
        DOT(a10,w1,x0) DOT(a11,w1,x1) DOT(a12,w1,x2) DOT(a13,w1,x3)
      }
      CMB3(a00) CMB3(a01) CMB3(a02) CMB3(a03)
      CMB3(a10) CMB3(a11) CMB3(a12) CMB3(a13)
      if (kq8 == 0){
        g01d[kk0] = a00;       g01d[kk0+1] = a10;
        g01d[128+kk0] = a01;   g01d[128+kk0+1] = a11;
        g01d[256+kk0] = a02;   g01d[256+kk0+1] = a12;
        g01d[384+kk0] = a03;   g01d[384+kk0+1] = a13;
      }
    }
    __syncthreads();
    // --- D2a: logits over t' (kk 2-split) + softmax partials
    {
      const float* hpb = hp + bbA*8320 + tlA;
      const float* gg = g01d + bbA*128;
      float a = 0.f;
      #pragma unroll 8
      for (int q = 0; q < 64; ++q){
        const int kk = kqA*64 + q;
        a += wd2[kk] * fast_tanh(hpb[kk*65] + gg[kk]);
      }
      a += __shfl_xor(a, 1, 64);
      a += bd2;
      const float m = wave_max(a);
      const float pe = exp2f_((a-m)*L2E);
      const float s = wave_sum(pe)*0.5f;               // kq-duplicated
      if ((tid & 63) == 0){ pm[bbA*2+tlh] = m; psu[bbA*2+tlh] = s; }
      if (kqA == 0) lraw[bbA*64 + tlA] = a;
    }
    __syncthreads();
    // --- D2b: softmax finish in place
    if (tid < 256){
      const int bb = tid >> 6;
      const float m0 = pm[bb*2], m1 = pm[bb*2+1];
      const float gm = fmaxf(m0,m1);
      const float tot = psu[bb*2]*exp2f_((m0-gm)*L2E) + psu[bb*2+1]*exp2f_((m1-gm)*L2E);
      lraw[tid] = exp2f_((lraw[tid]-gm)*L2E)*rcp_(tot);
    }
    __syncthreads();
    // --- D2c: parts[bb][h] = sum_t' a[t']*hexp[b][t'][h]; din partial folded
    {
      const float* he = ws + heBase;
      const float* av = lraw + bbC*64;
      float a = 0.f;
      #pragma unroll 8
      for (int t2 = 0; t2 < 64; ++t2)
        a += av[t2] * he[t2*128];
      parts[bbC*128 + hC] = a;
      float v = a * wdin_h;
      v = wave_sum(v);
      if ((tid & 63) == 0) dpart[bbC*2+hh] = v;
    }
    __syncthreads();
    // --- D3: layer0 gates (K=128 h0, 4-split) + bias + din rank-1
    {
      const float xd0 = p.input[(size_t)(b0+0)*8192 + t*128];
      const float xd1 = p.input[(size_t)(b0+1)*8192 + t*128];
      const float xd2 = p.input[(size_t)(b0+2)*8192 + t*128];
      const float xd3 = p.input[(size_t)(b0+3)*8192 + t*128];
      const float dn0 = dpart[0]+dpart[1] + xd0*dinw128 + dinbv;
      const float dn1 = dpart[2]+dpart[3] + xd1*dinw128 + dinbv;
      const float dn2 = dpart[4]+dpart[5] + xd2*dinw128 + dinbv;
      const float dn3 = dpart[6]+dpart[7] + xd3*dinw128 + dinbv;
      DECL16
      #pragma unroll
      for (int kg = 0; kg < 8; ++kg){
        const int idx = (((kg + kq4*2) & 7) << 2);
        const float4 wA = *(const float4*)(p.dWhh0 + offD3 + idx);
        const float4 wB = *(const float4*)(p.dWhh0 + offD3 + 128 + idx);
        const float4 wC = *(const float4*)(p.dWhh0 + offD3 + 256 + idx);
        const float4 wD = *(const float4*)(p.dWhh0 + offD3 + 384 + idx);
        const float4 xA = *(const float4*)(Sd + k0d3 + idx);
        const float4 xB = *(const float4*)(Sd + 384 + k0d3 + idx);
        const float4 xC = *(const float4*)(Sd + 768 + k0d3 + idx);
        const float4 xD = *(const float4*)(Sd + 1152 + k0d3 + idx);
        GEMM16(wA,wB,wC,wD,xA,xB,xC,xD);
      }
      CMB2ALL16
      if (kq4 == 0){
        *(float4*)(gp + j0)        = make_float4(a00+bias0d4.x+dn0*dW0v.x, a10+bias0d4.y+dn0*dW0v.y, a20+bias0d4.z+dn0*dW0v.z, a30+bias0d4.w+dn0*dW0v.w);
        *(float4*)(gp + 512 + j0)  = make_float4(a01+bias0d4.x+dn1*dW0v.x, a11+bias0d4.y+dn1*dW0v.y, a21+bias0d4.z+dn1*dW0v.z, a31+bias0d4.w+dn1*dW0v.w);
        *(float4*)(gp + 1024 + j0) = make_float4(a02+bias0d4.x+dn2*dW0v.x, a12+bias0d4.y+dn2*dW0v.y, a22+bias0d4.z+dn2*dW0v.z, a32+bias0d4.w+dn2*dW0v.w);
        *(float4*)(gp + 1536 + j0) = make_float4(a03+bias0d4.x+dn3*dW0v.x, a13+bias0d4.y+dn3*dW0v.y, a23+bias0d4.z+dn3*dW0v.z, a33+bias0d4.w+dn3*dW0v.w);
      }
    }
    __syncthreads();
    // --- A2: update h0, c0
    {
      const float* g = gp + bbU*512;
      const float gi=g[uU], gf=g[128+uU], gg2=g[256+uU], go=g[384+uU];
      const float c = sigm(gf)*c0s[tid] + sigm(gi)*fast_tanh(gg2);
      c0s[tid] = c;
      Sd[bbU*384 + uU] = sigm(go)*fast_tanh(c);
    }
    __syncthreads();
    // --- D4: layer1 gates (K=256 h0|h1, 4-split)
    {
      DECL16
      #pragma unroll 4
      for (int kg = 0; kg < 16; ++kg){
        const int idx = (((kg + kq4*2) & 15) << 2);
        const float4 wA = *(const float4*)(ws + offD4 + idx);
        const float4 wB = *(const float4*)(ws + offD4 + 256 + idx);
        const float4 wC = *(const float4*)(ws + offD4 + 512 + idx);
        const float4 wD = *(const float4*)(ws + offD4 + 768 + idx);
        const float4 xA = *(const float4*)(Sd + k0d4 + idx);
        const float4 xB = *(const float4*)(Sd + 384 + k0d4 + idx);
        const float4 xC = *(const float4*)(Sd + 768 + k0d4 + idx);
        const float4 xD = *(const float4*)(Sd + 1152 + k0d4 + idx);
        GEMM16(wA,wB,wC,wD,xA,xB,xC,xD);
      }
      CMB2ALL16
      if (kq4 == 0){
        *(float4*)(gp + j0)        = make_float4(a00+bias1d4.x, a10+bias1d4.y, a20+bias1d4.z, a30+bias1d4.w);
        *(float4*)(gp + 512 + j0)  = make_float4(a01+bias1d4.x, a11+bias1d4.y, a21+bias1d4.z, a31+bias1d4.w);
        *(float4*)(gp + 1024 + j0) = make_float4(a02+bias1d4.x, a12+bias1d4.y, a22+bias1d4.z, a32+bias1d4.w);
        *(float4*)(gp + 1536 + j0) = make_float4(a03+bias1d4.x, a13+bias1d4.y, a23+bias1d4.z, a33+bias1d4.w);
      }
    }
    __syncthreads();
    // --- A3: update h1, c1
    {
      const float* g = gp + bbU*512;
      const float gi=g[uU], gf=g[128+uU], gg2=g[256+uU], go=g[384+uU];
      const float c = sigm(gf)*Sd[bbU*384+256+uU] + sigm(gi)*fast_tanh(gg2);
      Sd[bbU*384+256+uU] = c;
      Sd[bbU*384+128+uU] = sigm(go)*fast_tanh(c);
    }
    __syncthreads();
  }
  // --- final projection
  if (tid < 256){
    const int bb = tid>>6, l = tid&63;
    float v = Sd[bb*384+128+l]*p.projW[l] + Sd[bb*384+192+l]*p.projW[64+l]
            + parts[bb*128+l]*p.projW[128+l] + parts[bb*128+64+l]*p.projW[192+l];
    v = wave_sum(v);
    if (l == 0) p.out[b0 + bb] = v + p.projb[0];
  }
}

extern "C" void kernel_launch(void* const* d_in, const int* in_sizes, int n_in,
                              void* d_out, int out_size, void* d_ws, size_t ws_size,
                              hipStream_t stream){
  Params p;
  p.input = (const float*)d_in[0];
  p.eWih0=(const float*)d_in[1];  p.eWhh0=(const float*)d_in[2];
  p.ebih0=(const float*)d_in[3];  p.ebhh0=(const float*)d_in[4];
  p.eWih1=(const float*)d_in[5];  p.eWhh1=(const float*)d_in[6];
  p.ebih1=(const float*)d_in[7];  p.ebhh1=(const float*)d_in[8];
  p.dWih0=(const float*)d_in[9];  p.dWhh0=(const float*)d_in[10];
  p.dbih0=(const float*)d_in[11]; p.dbhh0=(const float*)d_in[12];
  p.dWih1=(const float*)d_in[13]; p.dWhh1=(const float*)d_in[14];
  p.dbih1=(const float*)d_in[15]; p.dbhh1=(const float*)d_in[16];
  p.aW1=(const float*)d_in[17];   p.ab1=(const float*)d_in[18];
  p.aW2=(const float*)d_in[19];   p.ab2=(const float*)d_in[20];
  p.adW1=(const float*)d_in[21];  p.adb1=(const float*)d_in[22];
  p.adW2=(const float*)d_in[23];  p.adb2=(const float*)d_in[24];
  p.dinW=(const float*)d_in[25];  p.dinb=(const float*)d_in[26];
  p.projW=(const float*)d_in[27]; p.projb=(const float*)d_in[28];
  p.ws = (float*)d_ws;
  p.out = (float*)d_out;

  (void)hipFuncSetAttribute(reinterpret_cast<const void*>(k_enc),
      hipFuncAttributeMaxDynamicSharedMemorySize, ENC_LDS_FLOATS*4);
  (void)hipFuncSetAttribute(reinterpret_cast<const void*>(k_dec),
      hipFuncAttributeMaxDynamicSharedMemorySize, DEC_LDS_FLOATS*4);

  hipLaunchKernelGGL(k_prep,  dim3(128), dim3(256), 0, stream, p);
  hipLaunchKernelGGL(k_xproj, dim3(BATCH), dim3(256), 0, stream, p);
  hipLaunchKernelGGL(k_enc,   dim3(128), dim3(512), ENC_LDS_FLOATS*4, stream, p);
  hipLaunchKernelGGL(k_hproj, dim3(BATCH), dim3(256), 0, stream, p);
  hipLaunchKernelGGL(k_dec,   dim3(128), dim3(512), DEC_LDS_FLOATS*4, stream, p);
}

// Round 6
// 4871.975 us; speedup vs baseline: 1.3847x; 1.3847x over previous
//
#include <hip/hip_runtime.h>

#define BATCH 512
#define TT 64
#define II 128

// ---------------- workspace layout (floats) ----------------
#define OFF_Wr_e0 0                         // [512][256] rows: [Wih0(x,pad)|Whh0(h0)]
#define OFF_Wr_e1 (OFF_Wr_e0 + 512*256)     // [512][256] rows: [Wih1(h0)|Whh1(h1)]
#define OFF_Wr_d1 (OFF_Wr_e1 + 512*256)     // [512][256] rows: [dWih1(h0)|dWhh1(h1)]
#define OFF_bs0e  (OFF_Wr_d1 + 512*256)
#define OFF_bs1e  (OFF_bs0e + 512)
#define OFF_bs0d  (OFF_bs1e + 512)
#define OFF_bs1d  (OFF_bs0d + 512)
#define OFF_xprojT (OFF_bs1d + 512)          // [B][64j][128e]
#define OFF_hexp   (OFF_xprojT + BATCH*8192) // [B][64t][128k]
#define OFF_hprojT (OFF_hexp + BATCH*8192)   // [B][128kk][64t]

struct Params {
  const float* input;
  const float *eWih0, *eWhh0, *ebih0, *ebhh0, *eWih1, *eWhh1, *ebih1, *ebhh1;
  const float *dWih0, *dWhh0, *dbih0, *dbhh0, *dWih1, *dWhh1, *dbih1, *dbhh1;
  const float *aW1, *ab1, *aW2, *ab2;
  const float *adW1, *adb1, *adW2, *adb2;
  const float *dinW, *dinb, *projW, *projb;
  float* ws;
  float* out;
};

#define L2E 1.4426950408889634f

__device__ __forceinline__ float exp2f_(float x){ return __builtin_amdgcn_exp2f(x); }
__device__ __forceinline__ float rcp_(float x){ return __builtin_amdgcn_rcpf(x); }
__device__ __forceinline__ float fast_tanh(float x){
  float t = exp2f_(x * 2.8853900817779268f);   // e^{2x}
  return 1.f - 2.f * rcp_(t + 1.f);
}
__device__ __forceinline__ float sigm(float x){
  return rcp_(1.f + exp2f_(-x * L2E));
}
__device__ __forceinline__ float wave_max(float v){
  #pragma unroll
  for (int o = 32; o > 0; o >>= 1) v = fmaxf(v, __shfl_xor(v, o, 64));
  return v;
}
__device__ __forceinline__ float wave_sum(float v){
  #pragma unroll
  for (int o = 32; o > 0; o >>= 1) v += __shfl_xor(v, o, 64);
  return v;
}

#define DOT(A,W,X) A += (W).x*(X).x + (W).y*(X).y + (W).z*(X).z + (W).w*(X).w;

// ---------------- prep ----------------
__global__ __launch_bounds__(256) void k_prep(Params p){
  float* ws = p.ws;
  const int gid = blockIdx.x*256 + threadIdx.x;
  const int gsz = gridDim.x*256;
  for (int i = gid; i < 512*256; i += gsz){
    const int j = i >> 8, k = i & 255;
    ws[OFF_Wr_e0 + i] = (k < 128) ? ((k < 127) ? p.eWih0[j*127 + k] : 0.f)
                                  : p.eWhh0[j*128 + (k-128)];
    ws[OFF_Wr_e1 + i] = (k < 128) ? p.eWih1[j*128 + k] : p.eWhh1[j*128 + (k-128)];
    ws[OFF_Wr_d1 + i] = (k < 128) ? p.dWih1[j*128 + k] : p.dWhh1[j*128 + (k-128)];
  }
  for (int i = gid; i < 512; i += gsz){
    ws[OFF_bs0e+i] = p.ebih0[i]+p.ebhh0[i];
    ws[OFF_bs1e+i] = p.ebih1[i]+p.ebhh1[i];
    ws[OFF_bs0d+i] = p.dbih0[i]+p.dbhh0[i];
    ws[OFF_bs1d+i] = p.dbih1[i]+p.dbhh1[i];
  }
}

// ---------------- xprojT[b][j][e] ----------------
__global__ __launch_bounds__(256) void k_xproj(Params p){
  __shared__ float xin[64][128];
  __shared__ float w1x[64][64];
  __shared__ float b1s[64];
  const int b = blockIdx.x, tid = threadIdx.x;
  const float* inb = p.input + (size_t)b*(TT*II);
  for (int i = tid; i < 64*128; i += 256){
    const int k = i >> 7, e = i & 127;
    xin[k][e] = (e < 127) ? inb[k*II + 1 + e] : 0.f;
  }
  for (int i = tid; i < 64*64; i += 256){
    const int j = i >> 6, k = i & 63;
    w1x[j][k] = p.aW1[j*320 + 256 + k];
  }
  if (tid < 64) b1s[tid] = p.ab1[tid];
  __syncthreads();
  float* outb = p.ws + OFF_xprojT + (size_t)b*8192;
  for (int i = tid; i < 64*128; i += 256){
    const int j = i >> 7, e = i & 127;
    float acc = b1s[j];
    #pragma unroll 8
    for (int k = 0; k < 64; ++k) acc += xin[k][e] * w1x[j][k];
    outb[i] = acc;
  }
}

// ---------------- hprojT[b][kk][t] ----------------
__global__ __launch_bounds__(256) void k_hproj(Params p){
  __shared__ float hx[64][129];
  __shared__ float bs[128];
  const int b = blockIdx.x, tid = threadIdx.x;
  const float* hb = p.ws + OFF_hexp + (size_t)b*8192;
  for (int i = tid; i < 64*128; i += 256) hx[i>>7][i&127] = hb[i];
  if (tid < 128) bs[tid] = p.adb1[tid];
  __syncthreads();
  float* outb = p.ws + OFF_hprojT + (size_t)b*8192;
  for (int i = tid; i < 128*64; i += 256){
    const int kk = i >> 6, t2 = i & 63;
    const float* w = p.adW1 + kk*384 + 256;
    float acc = bs[kk];
    #pragma unroll 8
    for (int k = 0; k < 128; ++k) acc += hx[t2][k] * w[k];
    outb[i] = acc;
  }
}

// ---------------- encoder: 256 blocks x 2 batches, 512 threads --------------
// LDS floats: xp 16384 | Se 1024 | c0s 256 | gpA 1024 | gpB 1024 | g01s 128
//             w2 64 | pm 8 | psu 8  = 19920 (79,680 B)
#define ENC_LDS_FLOATS (16384+1024+256+1024+1024+128+64+8+8)
__global__ __launch_bounds__(512) void k_enc(Params p){
  extern __shared__ float sm[];
  float* xp   = sm;            // [bb][j][e] 2x64x128
  float* Se   = xp + 16384;    // [bb][x|h0|h1|c1] 2x512
  float* c0s  = Se + 1024;     // [bb][128]
  float* gpA  = c0s + 256;     // [bb][512]
  float* gpB  = gpA + 1024;
  float* g01s = gpB + 1024;    // [bb][64]
  float* w2   = g01s + 128;
  float* pm   = w2 + 64;
  float* psu  = pm + 8;
  const int tid = threadIdx.x;
  const int b0 = blockIdx.x*2;
  float* ws = p.ws;

  { const float4* xsrc = (const float4*)(ws + OFF_xprojT + (size_t)b0*8192);
    float4* xdst = (float4*)xp;
    for (int i = tid; i < 4096; i += 512) xdst[i] = xsrc[i]; }
  for (int i = tid; i < 1024; i += 512) Se[i] = 0.f;
  if (tid < 256) c0s[tid] = 0.f;
  if (tid < 64) w2[tid] = p.aW2[tid];
  const float b2 = p.ab2[0];

  // thread maps
  const int kqE = tid & 3, oE = tid >> 2, jjE = oE & 63, bbE = oE >> 6; // E1
  const int jh2 = tid & 1, o2 = tid >> 1, e2 = o2 & 127, bb2 = o2 >> 7; // E2
  const int qtr = (tid >> 6) & 3;
  const int jg = tid & 255, khg = tid >> 8;                             // gates
  const int uu = tid & 127, bbu = (tid >> 7) & 1;                       // updates

  const float bias0a = ws[OFF_bs0e + jg], bias0b = ws[OFF_bs0e + 256 + jg];
  const float bias1a = ws[OFF_bs1e + jg], bias1b = ws[OFF_bs1e + 256 + jg];
  const float* wE1 = p.aW1 + jjE*320 + kqE*64;
  const float* wE3 = ws + OFF_Wr_e0 + jg*256 + khg*128;   // row jg
  const float* wE4 = ws + OFF_Wr_e1 + jg*256 + khg*128;
  __syncthreads();

  for (int t = 0; t < TT; ++t){
    // --- E1: g01[bb][jj] over K=256 [h1|c1], 4-way K-split, shfl combine
    {
      const float* xbase = Se + bbE*512 + 256 + kqE*64;
      float a = 0.f;
      #pragma unroll
      for (int kg = 0; kg < 16; ++kg){
        const int idx = (((kg + kqE*4 + bbE*2) & 15) << 2);   // bank-rotated
        const float4 w = *(const float4*)(wE1 + idx);
        const float4 x = *(const float4*)(xbase + idx);
        DOT(a,w,x)
      }
      a += __shfl_xor(a,1,64); a += __shfl_xor(a,2,64);
      if (kqE == 0) g01s[bbE*64 + jjE] = a;
    }
    __syncthreads();
    // --- E2a: logits (2-way j-split) + per-wave softmax partials
    float accL;
    {
      const float* xpe = xp + bb2*8192 + e2;
      const float* gg = g01s + bb2*64 + jh2*32;
      const float* w2p = w2 + jh2*32;
      float a = 0.f;
      #pragma unroll 8
      for (int q = 0; q < 32; ++q)
        a += w2p[q] * fast_tanh(xpe[(jh2*32+q)*128] + gg[q]);
      a += __shfl_xor(a,1,64);
      a += b2;
      if (e2 == 127) a = -3.0e38f;
      accL = a;
      const float m = wave_max(a);
      const float pe = exp2f_((a - m)*L2E);
      const float s = wave_sum(pe)*0.5f;          // jh-duplicated
      if ((tid & 63) == 0){ pm[bb2*4+qtr] = m; psu[bb2*4+qtr] = s; }
    }
    __syncthreads();
    // --- E2c: finish softmax, Se.x = a * x_t (jh-dup writes identical)
    {
      const float m0=pm[bb2*4],m1=pm[bb2*4+1],m2=pm[bb2*4+2],m3=pm[bb2*4+3];
      const float gm = fmaxf(fmaxf(m0,m1),fmaxf(m2,m3));
      const float tot = psu[bb2*4]*exp2f_((m0-gm)*L2E) + psu[bb2*4+1]*exp2f_((m1-gm)*L2E)
                      + psu[bb2*4+2]*exp2f_((m2-gm)*L2E) + psu[bb2*4+3]*exp2f_((m3-gm)*L2E);
      const float aa = exp2f_((accL-gm)*L2E)*rcp_(tot);
      float xv = 0.f;
      if (e2 < 127) xv = p.input[(size_t)(b0+bb2)*8192 + t*128 + 1 + e2] * aa;
      Se[bb2*512 + e2] = xv;
    }
    __syncthreads();
    // --- E3: layer0 gates: rows jg, jg+256; operand Se[bb][0..255] (x|h0)
    {
      const float* ob0 = Se + khg*128;
      const float* ob1 = Se + 512 + khg*128;
      float a00,a01,a10,a11;
      a00 = a01 = khg ? 0.f : bias0a;
      a10 = a11 = khg ? 0.f : bias0b;
      #pragma unroll 8
      for (int kg = 0; kg < 32; ++kg){
        const float4 w  = *(const float4*)(wE3 + kg*4);
        const float4 w2_= *(const float4*)(wE3 + 65536 + kg*4);   // row jg+256
        const float4 x0 = *(const float4*)(ob0 + kg*4);
        const float4 x1 = *(const float4*)(ob1 + kg*4);
        DOT(a00,w,x0) DOT(a01,w,x1) DOT(a10,w2_,x0) DOT(a11,w2_,x1)
      }
      float* gp = khg ? gpB : gpA;
      gp[jg] = a00; gp[512 + jg] = a01;
      gp[256 + jg] = a10; gp[768 + jg] = a11;
    }
    __syncthreads();
    // --- A0: update h0, c0
    if (tid < 256){
      const int base = bbu*512 + uu;
      const float gi = gpA[base] + gpB[base];
      const float gf = gpA[base+128] + gpB[base+128];
      const float gg2= gpA[base+256] + gpB[base+256];
      const float go = gpA[base+384] + gpB[base+384];
      const float c = sigm(gf)*c0s[tid] + sigm(gi)*fast_tanh(gg2);
      c0s[tid] = c;
      Se[bbu*512 + 128 + uu] = sigm(go)*fast_tanh(c);
    }
    __syncthreads();
    // --- E4: layer1 gates: operand Se[bb][128..383] (h0|h1)
    {
      const float* ob0 = Se + 128 + khg*128;
      const float* ob1 = Se + 640 + khg*128;
      float a00,a01,a10,a11;
      a00 = a01 = khg ? 0.f : bias1a;
      a10 = a11 = khg ? 0.f : bias1b;
      #pragma unroll 8
      for (int kg = 0; kg < 32; ++kg){
        const float4 w  = *(const float4*)(wE4 + kg*4);
        const float4 w2_= *(const float4*)(wE4 + 65536 + kg*4);
        const float4 x0 = *(const float4*)(ob0 + kg*4);
        const float4 x1 = *(const float4*)(ob1 + kg*4);
        DOT(a00,w,x0) DOT(a01,w,x1) DOT(a10,w2_,x0) DOT(a11,w2_,x1)
      }
      float* gp = khg ? gpB : gpA;
      gp[jg] = a00; gp[512 + jg] = a01;
      gp[256 + jg] = a10; gp[768 + jg] = a11;
    }
    __syncthreads();
    // --- A1: update h1, c1, write hexp
    if (tid < 256){
      const int base = bbu*512 + uu;
      const float gi = gpA[base] + gpB[base];
      const float gf = gpA[base+128] + gpB[base+128];
      const float gg2= gpA[base+256] + gpB[base+256];
      const float go = gpA[base+384] + gpB[base+384];
      const float c = sigm(gf)*Se[bbu*512+384+uu] + sigm(gi)*fast_tanh(gg2);
      Se[bbu*512+384+uu] = c;
      const float h = sigm(go)*fast_tanh(c);
      Se[bbu*512+256+uu] = h;
      ws[OFF_hexp + (size_t)(b0+bbu)*8192 + t*128 + uu] = h;
    }
    __syncthreads();
  }
}

// ---------------- decoder: 256 blocks x 2 batches, 512 threads --------------
// LDS floats: hp 16640 | Sd 768 | c0s 256 | gpA 1024 | gpB 1024 | g01d 256
//             lraw 128 | pm 8 | psu 8 | dpart 8 | wd2 128 | parts 256 = 20504 (82,016 B)
#define DEC_LDS_FLOATS (16640+768+256+1024+1024+256+128+8+8+8+128+256)
__global__ __launch_bounds__(512) void k_dec(Params p){
  extern __shared__ float sm[];
  float* hp    = sm;             // [bb][kk][65] (pad)
  float* Sd    = hp + 16640;     // [bb][h0|h1|c1] 2x384
  float* c0s   = Sd + 768;       // [bb][128]
  float* gpA   = c0s + 256;
  float* gpB   = gpA + 1024;
  float* g01d  = gpB + 1024;     // [bb][128]
  float* lraw  = g01d + 256;     // [bb][64]
  float* pm    = lraw + 128;
  float* psu   = pm + 8;
  float* dpart = psu + 8;
  float* wd2   = dpart + 8;
  float* parts = wd2 + 128;      // [bb][128]
  const int tid = threadIdx.x;
  const int b0 = blockIdx.x*2;
  float* ws = p.ws;

  { const float* hsrc = ws + OFF_hprojT + (size_t)b0*8192;
    for (int i = tid; i < 16384; i += 512){
      const int bb = i>>13, kk = (i>>6)&127, tl = i&63;
      hp[bb*8320 + kk*65 + tl] = hsrc[i];
    } }
  for (int i = tid; i < 768; i += 512) Sd[i] = 0.f;
  if (tid < 256) c0s[tid] = 0.f;
  if (tid < 128) wd2[tid] = p.adW2[tid];
  const float bd2 = p.adb2[0];

  // thread maps
  const int kh1 = tid & 1, o1 = tid >> 1, kk1 = o1 & 127, bb1 = o1 >> 7;  // D1
  const int kqa = tid & 3, oa = tid >> 2, tla = oa & 63, bba = oa >> 6;   // D2a
  const int qtr = (tid >> 6) & 3;
  const int thc = tid & 1, oc = tid >> 1, hc = oc & 127, bbc = oc >> 7;   // D2c
  const int jg = tid & 255, khg = tid >> 8;                               // gates
  const int uu = tid & 127, bbu = (tid >> 7) & 1;

  const float bias0da = ws[OFF_bs0d + jg], bias0db = ws[OFF_bs0d + 256 + jg];
  const float bias1da = ws[OFF_bs1d + jg], bias1db = ws[OFF_bs1d + 256 + jg];
  const float dW0a = p.dWih0[jg], dW0b = p.dWih0[256 + jg];
  const float dinw_hc = p.dinW[hc];
  const float dinw128 = p.dinW[128], dinbv = p.dinb[0];
  const float* wD1 = p.adW1 + kk1*384 + kh1*128;
  const float* wD3 = p.dWhh0 + jg*128 + khg*64;
  const float* wD4 = ws + OFF_Wr_d1 + jg*256 + khg*128;
  const float* heB = ws + OFF_hexp + (size_t)(b0+bbc)*8192 + hc;
  __syncthreads();

  for (int t = 0; t < TT; ++t){
    // --- D1: g01d[bb][kk] over K=256 [h1|c1], 2-way K-split
    {
      const float* xbase = Sd + bb1*384 + 128 + kh1*128;
      float a = 0.f;
      #pragma unroll 8
      for (int kg = 0; kg < 32; ++kg){
        const int idx = (((kg + kh1*4 + bb1*2) & 31) << 2);
        const float4 w = *(const float4*)(wD1 + idx);
        const float4 x = *(const float4*)(xbase + idx);
        DOT(a,w,x)
      }
      a += __shfl_xor(a,1,64);
      if (kh1 == 0) g01d[bb1*128 + kk1] = a;
    }
    __syncthreads();
    // --- D2a: logits over t' (4-way kk-split) + softmax partials
    {
      const float* hpb = hp + bba*8320 + tla;
      const float* gg = g01d + bba*128;
      float a = 0.f;
      #pragma unroll 8
      for (int q = 0; q < 32; ++q){
        const int kk = kqa*32 + ((q + kqa*8) & 31);   // bank-rotated
        a += wd2[kk] * fast_tanh(hpb[kk*65] + gg[kk]);
      }
      a += __shfl_xor(a,1,64); a += __shfl_xor(a,2,64);
      a += bd2;
      if (kqa == 0) lraw[bba*64 + tla] = a;
      const float m = wave_max(a);
      const float pe = exp2f_((a-m)*L2E);
      const float s = wave_sum(pe)*0.25f;     // 4x duplicated
      if ((tid & 63) == 0){ pm[bba*4+qtr] = m; psu[bba*4+qtr] = s; }
    }
    __syncthreads();
    // --- D2b: finish softmax in place
    if (tid < 128){
      const int bb = tid >> 6;
      const float m0=pm[bb*4],m1=pm[bb*4+1],m2=pm[bb*4+2],m3=pm[bb*4+3];
      const float gm = fmaxf(fmaxf(m0,m1),fmaxf(m2,m3));
      const float tot = psu[bb*4]*exp2f_((m0-gm)*L2E)+psu[bb*4+1]*exp2f_((m1-gm)*L2E)
                      +psu[bb*4+2]*exp2f_((m2-gm)*L2E)+psu[bb*4+3]*exp2f_((m3-gm)*L2E);
      lraw[tid] = exp2f_((lraw[tid]-gm)*L2E)*rcp_(tot);
    }
    __syncthreads();
    // --- D2c: parts[bb][h] (2-way t'-split) + din partial folded
    {
      const float* av = lraw + bbc*64 + thc*32;
      float a = 0.f;
      #pragma unroll 8
      for (int q = 0; q < 32; ++q) a += av[q] * heB[(thc*32+q)*128];
      a += __shfl_xor(a,1,64);
      if (thc == 0) parts[bbc*128 + hc] = a;
      float v = a * dinw_hc;
      v = wave_sum(v)*0.5f;                   // th-duplicated
      if ((tid & 63) == 0) dpart[bbc*4+qtr] = v;
    }
    __syncthreads();
    // --- D3: layer0 gates (K=128 h0, 2-way split) + bias + din rank-1
    {
      const float dn0 = dpart[0]+dpart[1]+dpart[2]+dpart[3]
                      + p.input[(size_t)(b0+0)*8192 + t*128]*dinw128 + dinbv;
      const float dn1 = dpart[4]+dpart[5]+dpart[6]+dpart[7]
                      + p.input[(size_t)(b0+1)*8192 + t*128]*dinw128 + dinbv;
      const float* ob0 = Sd + khg*64;
      const float* ob1 = Sd + 384 + khg*64;
      float a00,a01,a10,a11;
      if (khg){ a00=a01=a10=a11=0.f; }
      else {
        a00 = bias0da + dn0*dW0a; a01 = bias0da + dn1*dW0a;
        a10 = bias0db + dn0*dW0b; a11 = bias0db + dn1*dW0b;
      }
      #pragma unroll 8
      for (int kg = 0; kg < 16; ++kg){
        const float4 w  = *(const float4*)(wD3 + kg*4);
        const float4 w2_= *(const float4*)(wD3 + 32768 + kg*4);   // row jg+256
        const float4 x0 = *(const float4*)(ob0 + kg*4);
        const float4 x1 = *(const float4*)(ob1 + kg*4);
        DOT(a00,w,x0) DOT(a01,w,x1) DOT(a10,w2_,x0) DOT(a11,w2_,x1)
      }
      float* gp = khg ? gpB : gpA;
      gp[jg] = a00; gp[512 + jg] = a01;
      gp[256 + jg] = a10; gp[768 + jg] = a11;
    }
    __syncthreads();
    // --- A2: update h0, c0
    if (tid < 256){
      const int base = bbu*512 + uu;
      const float gi = gpA[base] + gpB[base];
      const float gf = gpA[base+128] + gpB[base+128];
      const float gg2= gpA[base+256] + gpB[base+256];
      const float go = gpA[base+384] + gpB[base+384];
      const float c = sigm(gf)*c0s[tid] + sigm(gi)*fast_tanh(gg2);
      c0s[tid] = c;
      Sd[bbu*384 + uu] = sigm(go)*fast_tanh(c);
    }
    __syncthreads();
    // --- D4: layer1 gates (K=256 h0|h1, 2-way split)
    {
      const float* ob0 = Sd + khg*128;
      const float* ob1 = Sd + 384 + khg*128;
      float a00,a01,a10,a11;
      a00 = a01 = khg ? 0.f : bias1da;
      a10 = a11 = khg ? 0.f : bias1db;
      #pragma unroll 8
      for (int kg = 0; kg < 32; ++kg){
        const float4 w  = *(const float4*)(wD4 + kg*4);
        const float4 w2_= *(const float4*)(wD4 + 65536 + kg*4);
        const float4 x0 = *(const float4*)(ob0 + kg*4);
        const float4 x1 = *(const float4*)(ob1 + kg*4);
        DOT(a00,w,x0) DOT(a01,w,x1) DOT(a10,w2_,x0) DOT(a11,w2_,x1)
      }
      float* gp = khg ? gpB : gpA;
      gp[jg] = a00; gp[512 + jg] = a01;
      gp[256 + jg] = a10; gp[768 + jg] = a11;
    }
    __syncthreads();
    // --- A3: update h1, c1
    if (tid < 256){
      const int base = bbu*512 + uu;
      const float gi = gpA[base] + gpB[base];
      const float gf = gpA[base+128] + gpB[base+128];
      const float gg2= gpA[base+256] + gpB[base+256];
      const float go = gpA[base+384] + gpB[base+384];
      const float c = sigm(gf)*Sd[bbu*384+256+uu] + sigm(gi)*fast_tanh(gg2);
      Sd[bbu*384+256+uu] = c;
      Sd[bbu*384+128+uu] = sigm(go)*fast_tanh(c);
    }
    __syncthreads();
  }
  // --- final projection
  if (tid < 128){
    const int bb = tid>>6, l = tid&63;
    float v = Sd[bb*384+128+l]*p.projW[l] + Sd[bb*384+192+l]*p.projW[64+l]
            + parts[bb*128+l]*p.projW[128+l] + parts[bb*128+64+l]*p.projW[192+l];
    v = wave_sum(v);
    if (l == 0) p.out[b0 + bb] = v + p.projb[0];
  }
}

extern "C" void kernel_launch(void* const* d_in, const int* in_sizes, int n_in,
                              void* d_out, int out_size, void* d_ws, size_t ws_size,
                              hipStream_t stream){
  Params p;
  p.input = (const float*)d_in[0];
  p.eWih0=(const float*)d_in[1];  p.eWhh0=(const float*)d_in[2];
  p.ebih0=(const float*)d_in[3];  p.ebhh0=(const float*)d_in[4];
  p.eWih1=(const float*)d_in[5];  p.eWhh1=(const float*)d_in[6];
  p.ebih1=(const float*)d_in[7];  p.ebhh1=(const float*)d_in[8];
  p.dWih0=(const float*)d_in[9];  p.dWhh0=(const float*)d_in[10];
  p.dbih0=(const float*)d_in[11]; p.dbhh0=(const float*)d_in[12];
  p.dWih1=(const float*)d_in[13]; p.dWhh1=(const float*)d_in[14];
  p.dbih1=(const float*)d_in[15]; p.dbhh1=(const float*)d_in[16];
  p.aW1=(const float*)d_in[17];   p.ab1=(const float*)d_in[18];
  p.aW2=(const float*)d_in[19];   p.ab2=(const float*)d_in[20];
  p.adW1=(const float*)d_in[21];  p.adb1=(const float*)d_in[22];
  p.adW2=(const float*)d_in[23];  p.adb2=(const float*)d_in[24];
  p.dinW=(const float*)d_in[25];  p.dinb=(const float*)d_in[26];
  p.projW=(const float*)d_in[27]; p.projb=(const float*)d_in[28];
  p.ws = (float*)d_ws;
  p.out = (float*)d_out;

  (void)hipFuncSetAttribute(reinterpret_cast<const void*>(k_enc),
      hipFuncAttributeMaxDynamicSharedMemorySize, ENC_LDS_FLOATS*4);
  (void)hipFuncSetAttribute(reinterpret_cast<const void*>(k_dec),
      hipFuncAttributeMaxDynamicSharedMemorySize, DEC_LDS_FLOATS*4);

  hipLaunchKernelGGL(k_prep,  dim3(128), dim3(256), 0, stream, p);
  hipLaunchKernelGGL(k_xproj, dim3(BATCH), dim3(256), 0, stream, p);
  hipLaunchKernelGGL(k_enc,   dim3(256), dim3(512), ENC_LDS_FLOATS*4, stream, p);
  hipLaunchKernelGGL(k_hproj, dim3(BATCH), dim3(256), 0, stream, p);
  hipLaunchKernelGGL(k_dec,   dim3(256), dim3(512), DEC_LDS_FLOATS*4, stream, p);
}